// Round 12
// baseline (2914.193 us; speedup 1.0000x reference)
//
#include <hip/hip_runtime.h>

#define TST   1024
#define OWNR  8            // own tile: 8 rows
#define OWNC  16           // own tile: 16 cols
#define HALO  8            // 8 rings -> 8 stages -> 2 RK4 steps per exchange
#define TROWS 24           // 8 + 2*8
#define TCOLS 32           // 16 + 2*8
#define NT    768          // 24x32 cells, 1/thread; 12 waves
#define NW    12
#define NB    512          // 32x16 tiles; 2 blocks per CU (the point of R12)

typedef float v4f __attribute__((ext_vector_type(4)));

#define AG __HIP_MEMORY_SCOPE_AGENT
__device__ __forceinline__ float agload (const float* p){ return __hip_atomic_load (p, __ATOMIC_RELAXED, AG); }
__device__ __forceinline__ int   agloadi(const int* p)  { return __hip_atomic_load (p, __ATOMIC_RELAXED, AG); }
__device__ __forceinline__ void  agstorei(int* p,int v) {         __hip_atomic_store(p, v, __ATOMIC_RELAXED, AG); }

// Device-scope (sc1) 16B accesses, coherent at Infinity Cache. Stamp rides in
// .w -> each halo cell self-validates. Load+waitcnt in ONE asm block.
__device__ __forceinline__ v4f ld16_dev(const v4f* p) {
    v4f r;
    asm volatile("global_load_dwordx4 %0, %1, off sc1\n\ts_waitcnt vmcnt(0)"
                 : "=v"(r) : "v"(p) : "memory");
    return r;
}
__device__ __forceinline__ void st16_dev(v4f* p, v4f v) {
    asm volatile("global_store_dwordx4 %0, %1, off sc1" :: "v"(p), "v"(v) : "memory");
}

__global__ void __launch_bounds__(NT)
mm_solver(const float* __restrict__ signal,
          const float* __restrict__ B_ext,
          const float* __restrict__ Msat,
          const float* __restrict__ src_mask,
          const float* __restrict__ probe_mask,
          float* __restrict__ out,
          float* __restrict__ ws)
{
    const int b  = (int)blockIdx.x;
    const int bx = b & 15, by = b >> 4;      // 32 tile-rows x 16 tile-cols
    const int t  = (int)threadIdx.x;
    const int tr = t >> 5, tc = t & 31;      // 24 rows x 32 cols, rank == t
    const int wv = t >> 6;                   // wave id 0..11

    // R12: 2 CO-RESIDENT BLOCKS PER CU. R11 showed the phase is latency/stall
    // bound (VALUBusy 49% at 1 block/CU: barrier arrival + lgkm drain + DS
    // latency + the group-start IF$ poll RTT stall the whole block with
    // nothing else to run). Tiles of own 8x16 -> 768 threads, 12 waves,
    // ~28.5KB LDS -> 2 independent blocks/CU interleave: one block's stalls
    // are filled by the other's issue. Cone predication keeps the extra halo
    // work at only ~+25% cell-gates/CU (shell formula: WH+2r(W+H)+2r^2).
    // Protocol/phases/predication are verbatim R11 with rectangular own.

    const int grow = by * OWNR - HALO + tr;
    const int gcol = bx * OWNC - HALO + tc;
    const bool inG = (grow >= 0 && grow < 256 && gcol >= 0 && gcol < 256);
    const bool own = (tr >= HALO && tr < HALO + OWNR && tc >= HALO && tc < HALO + OWNC);

    // Cone predication: dOwn = L1 distance to the own region (tile coords).
    // Participate in phase p iff dOwn <= budget(p). Proof as R11 (neighbor
    // distance differs by <=1; edge garbage never generated).
    const int dyO = (tr < HALO) ? (HALO - tr) : ((tr > HALO + OWNR - 1) ? (tr - (HALO + OWNR - 1)) : 0);
    const int dxO = (tc < HALO) ? (HALO - tc) : ((tc > HALO + OWNC - 1) ? (tc - (HALO + OWNC - 1)) : 0);
    const int dOwn = dxO + dyO;

    // ws: pub v4f[2][65536] (2MB) | privG float[TST] (4KB) | doneA int[NB]
    // (zeroed by hipMemsetAsync in kernel_launch before this dispatch)
    v4f*   pub   = (v4f*)ws;
    float* privG = ws + 2 * 65536 * 4;
    int*   doneA = (int*)(privG + TST);
    const int pubStride = 65536;

    __shared__ v4f  EB[2][TROWS * TCOLS];    // 24 KB exposure buffers
    __shared__ float sigS[TST];
    __shared__ float redS[NW];
    __shared__ float pmsS;

    // Phase sync = ONE hardware s_barrier per stage (8/group), 12 waves.
    // Double-buffer hazard proof unchanged from R7/R11 (verified): phase p
    // writes EB[p&1] -> lgkmcnt(0)+barrier -> reads EB[p&1]; the overwrite of
    // EB[(p+1)&1] (read at phase p-1) is separated from those reads by the
    // phase-p barrier. PSYNC is OUTSIDE all predicates.
#define PSYNC() do { \
    asm volatile("s_waitcnt lgkmcnt(0)" ::: "memory"); \
    __builtin_amdgcn_s_barrier(); \
    asm volatile("" ::: "memory"); \
} while (0)

    const bool lane0 = ((t & 63) == 0);

    // constants (identical fp expressions to the bitwise-validated kernels)
    const float invd   = (float)(1.0 / (double)((float)(50e-9 * 50e-9)));
    const float h      = (float)(1.7595e11 * 5e-12);
    const float hh     = (float)(0.5 * (1.7595e11 * 5e-12));
    const float h6     = (float)((1.7595e11 * 5e-12) / 6.0);
    const float alpha  = 0.01f;
    const float inv1a2 = (float)(1.0 / (1.0 + 0.01 * 0.01));

    const int growc = grow < 0 ? 0 : (grow > 255 ? 255 : grow);
    const int gcolc = gcol < 0 ? 0 : (gcol > 255 ? 255 : gcol);
    const int idxg  = growc * 256 + gcolc;
    const float bxv = B_ext[idxg], byv = B_ext[65536 + idxg], bzv = B_ext[131072 + idxg];
    const float ms  = Msat[idxg];
    const float sxv = src_mask[idxg], syv = src_mask[65536 + idxg], szv = src_mask[131072 + idxg];
    const float pm  = probe_mask[idxg];
    const float ce   = 7.3e-12f / ms;
    const float cdem = -(float)(4.0e-7 * 3.14159265358979323846) * ms;

    // Neighbor offsets: physical Neumann clamp (exact) + tile-edge clamp
    // (never consumed at a mattering stage under predication; kept verbatim).
    const int idx  = t;
    const int offU = ((tr < TROWS - 1) && (grow < 255)) ?  TCOLS : 0;
    const int offD = ((tr > 0)         && (grow > 0))   ? -TCOLS : 0;
    const int offR = ((tc < TCOLS - 1) && (gcol < 255)) ?  1 : 0;
    const int offL = ((tc > 0)         && (gcol > 0))   ? -1 : 0;

    const int slotOff = idxg;                 // poll slot (own: == publish slot)

    // relax() is bitwise identity; m0 = z-hat exactly. Group 0 needs no halo
    // poll; pub was memset to 0 -> stamp 0 < 1 = first polled I, so no
    // garbage stamp can validate. Owners also pre-stamp (0 / -1) as before.
    float mx = 0.0f, my = 0.0f, mz = 1.0f;

    if (own) {
        st16_dev(pub + slotOff,             (v4f){0.0f, 0.0f, 1.0f, __int_as_float(0)});
        st16_dev(pub + pubStride + slotOff, (v4f){0.0f, 0.0f, 1.0f, __int_as_float(-1)});
    }
    for (int k = t; k < TST; k += NT) sigS[k] = signal[k];
    __syncthreads();
    const bool pcell = own && (pm != 0.0f);
    const bool waveP = (__ballot(pcell) != 0ull);   // wave-uniform

    // Poll only cells that participate (dOwn <= 8).
    const bool haloT = inG && !own && (dOwn <= HALO);
    float ex, ey, ez, ax, ay, az, kx, ky, kz, btx, bty, btz;

#define STAGE(SB) do { \
    const v4f u = EB[SB][idx + offU]; \
    const v4f d = EB[SB][idx + offD]; \
    const v4f r = EB[SB][idx + offR]; \
    const v4f l = EB[SB][idx + offL]; \
    float lx = ((u.x + d.x - 2.0f * ex) + (r.x + l.x - 2.0f * ex)) * invd; \
    float ly = ((u.y + d.y - 2.0f * ey) + (r.y + l.y - 2.0f * ey)) * invd; \
    float lz = ((u.z + d.z - 2.0f * ez) + (r.z + l.z - 2.0f * ez)) * invd; \
    float Bx = btx + ce * lx; \
    float By = bty + ce * ly; \
    float Bz = btz + ce * lz + cdem * ez; \
    float cx = ey * Bz - ez * By; \
    float cy = ez * Bx - ex * Bz; \
    float cz = ex * By - ey * Bx; \
    float dx = ey * cz - ez * cy; \
    float dy = ez * cx - ex * cz; \
    float dz = ex * cy - ey * cx; \
    kx = -(cx + alpha * dx) * inv1a2; \
    ky = -(cy + alpha * dy) * inv1a2; \
    kz = -(cz + alpha * dz) * inv1a2; \
} while (0)

#define WRE(DB) do { EB[DB][idx] = (v4f){ex, ey, ez, 0.0f}; } while (0)

// One full RK4 step with cone predication (verbatim R11 structure).
#define RK4_STEP(S, A) do { \
    if (dOwn <= (A)) { \
        btx = bxv + (S) * sxv;  bty = byv + (S) * syv;  btz = bzv + (S) * szv; \
        ex = mx; ey = my; ez = mz; \
        WRE(0); \
    } \
    PSYNC(); \
    if (dOwn <= (A) - 1) { \
        STAGE(0);                          /* k1 */ \
        ax = kx; ay = ky; az = kz; \
        ex = mx + hh * kx; ey = my + hh * ky; ez = mz + hh * kz; \
        WRE(1); \
    } \
    PSYNC(); \
    if (dOwn <= (A) - 2) { \
        STAGE(1);                          /* k2 */ \
        ax += 2.0f * kx; ay += 2.0f * ky; az += 2.0f * kz; \
        ex = mx + hh * kx; ey = my + hh * ky; ez = mz + hh * kz; \
        WRE(0); \
    } \
    PSYNC(); \
    if (dOwn <= (A) - 3) { \
        STAGE(0);                          /* k3 */ \
        ax += 2.0f * kx; ay += 2.0f * ky; az += 2.0f * kz; \
        ex = mx + h * kx; ey = my + h * ky; ez = mz + h * kz; \
        WRE(1); \
    } \
    PSYNC(); \
    if (dOwn <= (A) - 4) { \
        STAGE(1);                          /* k4 */ \
        ax += kx; ay += ky; az += kz; \
        mx += h6 * ax; my += h6 * ay; mz += h6 * az; \
    } \
} while (0)

// Probe: shared global accumulator privG[TST] (zeroed pre-launch by memset);
// <=6 blocks contain probe cells, ~1 atomic each per step -> no contention.
#define PROBE(I_) do { \
    if (waveP) { \
        float c = pcell ? mx * ms * pm : 0.0f; \
        _Pragma("unroll") \
        for (int off = 32; off > 0; off >>= 1) c += __shfl_down(c, off, 64); \
        if (lane0) atomicAdd(&privG[(I_)], c); \
    } \
} while (0)

    for (int i = 0; i < TST; i += 2) {
        const int I = i >> 1;                 // 2-step group index

        // Halo refresh ONCE per group: poll my cell's stamped slot (parity
        // I&1) until stamp>=I. Skipped at I==0 (m_0 analytic). Miss ->
        // s_sleep(1) backoff. Cross-block chain strictly decreases group
        // index -> no premature overwrite, no deadlock (proof as R5-R11).
        if (haloT && I) {
            const v4f* p = pub + (I & 1) * pubStride + slotOff;
            for (;;) {
                v4f hv = ld16_dev(p);
                if (__float_as_int(hv.w) >= I) { mx = hv.x; my = hv.y; mz = hv.z; break; }
                __builtin_amdgcn_s_sleep(1);
            }
        }

        RK4_STEP(sigS[i],     8);             // step A -> m_{i+1}
        PROBE(i);
        RK4_STEP(sigS[i + 1], 4);             // step B -> m_{i+2}
        PROBE(i + 1);

        // publish m_{i+2}, stamp I+1, parity (I+1)&1 (fire-and-forget, global)
        if (own) st16_dev(pub + ((I + 1) & 1) * pubStride + slotOff,
                          (v4f){mx, my, mz, __int_as_float(I + 1)});
    }

    // ---- finalize ----
    __syncthreads();   // TRUE barrier: drains vmcnt -> publishes/atomics done
    if (t == 0) agstorei(&doneA[b], 0x5D0000);

    if (b == 0) {
        if (t < NB) {
            for (;;) { if (agloadi(&doneA[t]) == 0x5D0000) break;
                       __builtin_amdgcn_s_sleep(8); }
        }
        __syncthreads();
        float ps = 0.0f;
        for (int k = t; k < 65536; k += NT) ps += probe_mask[k];
        #pragma unroll
        for (int off = 32; off > 0; off >>= 1) ps += __shfl_down(ps, off, 64);
        if (lane0) redS[wv] = ps;
        __syncthreads();
        if (t == 0) { float q = 0.0f; for (int w = 0; w < NW; ++w) q += redS[w]; pmsS = q; }
        __syncthreads();
        const float pms = pmsS;
        for (int o = t; o < TST; o += NT) out[o] = agload(&privG[o]) / pms;
    }
}

extern "C" void kernel_launch(void* const* d_in, const int* in_sizes, int n_in,
                              void* d_out, int out_size, void* d_ws, size_t ws_size,
                              hipStream_t stream)
{
    const float* signal = (const float*)d_in[0];
    const float* B_ext  = (const float*)d_in[1];
    const float* Msat   = (const float*)d_in[2];
    const float* src    = (const float*)d_in[3];
    const float* probe  = (const float*)d_in[4];
    float* out = (float*)d_out;
    float* ws  = (float*)d_ws;

    void* args[] = { &signal, &B_ext, &Msat, &src, &probe, &out, &ws };
    (void)in_sizes; (void)n_in; (void)out_size; (void)ws_size;

    // Explicit zero of the used ws region (pub stamps + privG + doneA):
    // async memset on the stream, graph-capturable, ~1us. Removes all
    // reliance on harness-side ws zeroing for stamp/flag/accumulator init.
    const size_t wsUsed = (size_t)(2 * 65536 * 4 + TST) * sizeof(float)
                        + (size_t)NB * sizeof(int);
    hipMemsetAsync(d_ws, 0, wsUsed, stream);

    // 512 blocks (own 8x16 tiles, 8-deep halo) x 768 threads, 12 waves,
    // ~28.5KB LDS -> 2 co-resident blocks per CU (24/32 waves): one block's
    // barrier/poll stalls are filled by the other block's issue (R11 showed
    // 50% issue-idle at 1 block/CU). Cone predication + hw-barrier phases +
    // stamped IF$ exchange every 2 RK4 steps, verbatim R11 protocol.
    hipLaunchCooperativeKernel(reinterpret_cast<void*>(mm_solver),
                               dim3(NB), dim3(NT), args, 0, stream);
}

// Round 13
// 2672.485 us; speedup vs baseline: 1.0904x; 1.0904x over previous
//
#include <hip/hip_runtime.h>

#define TST   1024
#define OWN   16           // own tile: 16x16
#define HALO  8            // 8 rings -> 8 stages -> 2 RK4 steps per exchange
#define TDIM  32           // 32x32 tile = own 16x16 + 8-halo
#define NT    1024         // 16 waves; wave w owns tile rows {2w, 2w+1}
#define NW    16
#define NB    256          // 16x16 blocks, one per CU

typedef float v4f __attribute__((ext_vector_type(4)));

#define AG __HIP_MEMORY_SCOPE_AGENT
__device__ __forceinline__ float agload (const float* p){ return __hip_atomic_load (p, __ATOMIC_RELAXED, AG); }
__device__ __forceinline__ int   agloadi(const int* p)  { return __hip_atomic_load (p, __ATOMIC_RELAXED, AG); }
__device__ __forceinline__ void  agstoref(float* p,float v){      __hip_atomic_store(p, v, __ATOMIC_RELAXED, AG); }
__device__ __forceinline__ void  agstorei(int* p,int v) {         __hip_atomic_store(p, v, __ATOMIC_RELAXED, AG); }

// Device-scope (sc1) 16B accesses, coherent at Infinity Cache. Stamp rides in
// .w -> each halo cell self-validates. Load+waitcnt in ONE asm block.
__device__ __forceinline__ v4f ld16_dev(const v4f* p) {
    v4f r;
    asm volatile("global_load_dwordx4 %0, %1, off sc1\n\ts_waitcnt vmcnt(0)"
                 : "=v"(r) : "v"(p) : "memory");
    return r;
}
__device__ __forceinline__ void st16_dev(v4f* p, v4f v) {
    asm volatile("global_store_dwordx4 %0, %1, off sc1" :: "v"(p), "v"(v) : "memory");
}

__global__ void __launch_bounds__(NT)
mm_solver(const float* __restrict__ signal,
          const float* __restrict__ B_ext,
          const float* __restrict__ Msat,
          const float* __restrict__ src_mask,
          const float* __restrict__ probe_mask,
          float* __restrict__ out,
          float* __restrict__ ws)
{
    const int b  = (int)blockIdx.x;
    const int bx = b & 15, by = b >> 4;
    const int t  = (int)threadIdx.x;
    const int tr = t >> 5, tc = t & 31;      // 32-wide rows, rank == t
    const int wv = t >> 6;                   // wave id 0..15

    const int grow = by * OWN - HALO + tr;
    const int gcol = bx * OWN - HALO + tc;
    const bool inG = (grow >= 0 && grow < 256 && gcol >= 0 && gcol < 256);
    const bool own = (tr >= HALO && tr < HALO + OWN && tc >= HALO && tc < HALO + OWN);

    // Cone predication (R11, verified): participate in the phase-q write iff
    // dOwn <= 8-q; read phase-(q-1) data iff dOwn <= 8-q (same predicate).
    const int dyO = (tr < HALO) ? (HALO - tr) : ((tr > 23) ? (tr - 23) : 0);
    const int dxO = (tc < HALO) ? (HALO - tc) : ((tc > 23) ? (tc - 23) : 0);
    const int dOwn = dxO + dyO;
    // Wave row-distance (wave = rows {2w,2w+1}): min dy over its rows.
    const int dyW = (wv < 4) ? (7 - 2 * wv) : ((wv >= 12) ? (2 * wv - 23) : 0);

    // ws: pub v4f[2][65536] (2MB) | priv float[NB][TST] (1MB) | doneA int[NB]
    v4f*   pub   = (v4f*)ws;
    float* priv  = ws + 2 * 65536 * 4;
    int*   doneA = (int*)(priv + NB * TST);
    const int pubStride = 65536;

    __shared__ v4f  EB[2][TDIM * TDIM];      // 32 KB exposure buffers
    __shared__ float sigS[TST];
    __shared__ int  wctr[NW + 2];            // per-wave phase counters + sentinels
    __shared__ int   hasP;
    __shared__ int   pfl[NB];
    __shared__ float redS[NW];
    __shared__ float pmsS;

    // R13 sync = R5's PROVEN per-wave spin counters + R11's PROVEN cone
    // predication. Counter semantics: ctr=g  <=>  my phase-g write AND my
    // phase-(g-1) read are complete (lgkmcnt(0) before PUB covers both).
    // Rules (derived, see round notes):
    //  * phase-q block: SPIN_NBR(g0+q-1) -> STAGE(phase q-1 data) -> WRE(q)
    //    -> PUB(g0+q). Write/read predicates coincide (8-q), so every writer
    //    at q spun at q-1 -> the overwrite-of-(q-2) rule holds under
    //    predication.
    //  * waves inactive at q publish the counter unconditionally (cheap) ->
    //    all waits terminate; far waves burst-publish and RACE to the next
    //    group's IF$ poll -> poll RTT overlaps central waves' phases 2-7.
    //  * group start: universal SPIN_NBR(g0-1) before the phase-0 write
    //    (covers every wave's last buffer-0 overwrite; central = exact).
    // Cross-block stamp chain unchanged (R5-R11): strictly decreasing group
    // index, base at group 1 -> no deadlock, no premature overwrite.
    volatile int* cl  = (volatile int*)&wctr[wv];        // left nbr (sentinel @0)
    volatile int* cr  = (volatile int*)&wctr[wv + 2];    // right nbr (sentinel @NW+1)
    volatile int* cme = (volatile int*)&wctr[wv + 1];
    const bool lane0 = ((t & 63) == 0);

#define PUB_CTR(G) do { \
    asm volatile("s_waitcnt lgkmcnt(0)" ::: "memory"); \
    if (lane0) *cme = (G); \
    asm volatile("" ::: "memory"); \
} while (0)
#define SPIN_NBR(G) do { \
    while (*cl < (G)) {} \
    while (*cr < (G)) {} \
    asm volatile("" ::: "memory"); \
} while (0)

    // constants (identical fp expressions to the bitwise-validated kernels)
    const float invd   = (float)(1.0 / (double)((float)(50e-9 * 50e-9)));
    const float h      = (float)(1.7595e11 * 5e-12);
    const float hh     = (float)(0.5 * (1.7595e11 * 5e-12));
    const float h6     = (float)((1.7595e11 * 5e-12) / 6.0);
    const float alpha  = 0.01f;
    const float inv1a2 = (float)(1.0 / (1.0 + 0.01 * 0.01));

    const int growc = grow < 0 ? 0 : (grow > 255 ? 255 : grow);
    const int gcolc = gcol < 0 ? 0 : (gcol > 255 ? 255 : gcol);
    const int idxg  = growc * 256 + gcolc;
    const float bxv = B_ext[idxg], byv = B_ext[65536 + idxg], bzv = B_ext[131072 + idxg];
    const float ms  = Msat[idxg];
    const float sxv = src_mask[idxg], syv = src_mask[65536 + idxg], szv = src_mask[131072 + idxg];
    const float pm  = probe_mask[idxg];
    const float ce   = 7.3e-12f / ms;
    const float cdem = -(float)(4.0e-7 * 3.14159265358979323846) * ms;

    // Neighbor offsets: physical Neumann clamp (exact) + tile-edge clamp
    // (never consumed at a mattering stage under predication; kept verbatim).
    const int idx  = t;
    const int offU = ((tr < TDIM - 1) && (grow < 255)) ?  TDIM : 0;
    const int offD = ((tr > 0)        && (grow > 0))   ? -TDIM : 0;
    const int offR = ((tc < TDIM - 1) && (gcol < 255)) ?  1 : 0;
    const int offL = ((tc > 0)        && (gcol > 0))   ? -1 : 0;

    const int slotOff = idxg;                 // poll slot (own: == publish slot)

    // relax() is bitwise identity; m0 = z-hat exactly. Group 0 needs no halo
    // poll; owners pre-stamp parity-1 with -1 so no garbage stamp validates.
    float mx = 0.0f, my = 0.0f, mz = 1.0f;

    if (own) {
        st16_dev(pub + slotOff,             (v4f){0.0f, 0.0f, 1.0f, __int_as_float(0)});
        st16_dev(pub + pubStride + slotOff, (v4f){0.0f, 0.0f, 1.0f, __int_as_float(-1)});
    }
    for (int k = t; k < TST; k += NT) sigS[k] = signal[k];
    if (t < NW + 2)
        wctr[t] = ((t == 0) || (t == NW + 1)) ? 0x7fffffff : -1;   // sentinels
    if (t == 40) hasP = 0;
    __syncthreads();
    const bool pcell = own && (pm != 0.0f);
    if (pcell) atomicOr(&hasP, 1);
    const bool waveP = (__ballot(pcell) != 0ull);   // wave-uniform (central waves)
    __syncthreads();
    const int hasPr = hasP;
    if (hasPr) for (int k = t; k < TST; k += NT) agstoref(&priv[b * TST + k], 0.0f);
    __syncthreads();   // drain zero-stores before step-0 probe atomics

    const bool haloT = inG && !own && (dOwn <= HALO);
    float ex, ey, ez, ax, ay, az, kx, ky, kz, btx, bty, btz;

#define STAGE(SB) do { \
    const v4f u = EB[SB][idx + offU]; \
    const v4f d = EB[SB][idx + offD]; \
    const v4f r = EB[SB][idx + offR]; \
    const v4f l = EB[SB][idx + offL]; \
    float lx = ((u.x + d.x - 2.0f * ex) + (r.x + l.x - 2.0f * ex)) * invd; \
    float ly = ((u.y + d.y - 2.0f * ey) + (r.y + l.y - 2.0f * ey)) * invd; \
    float lz = ((u.z + d.z - 2.0f * ez) + (r.z + l.z - 2.0f * ez)) * invd; \
    float Bx = btx + ce * lx; \
    float By = bty + ce * ly; \
    float Bz = btz + ce * lz + cdem * ez; \
    float cx = ey * Bz - ez * By; \
    float cy = ez * Bx - ex * Bz; \
    float cz = ex * By - ey * Bx; \
    float dx = ey * cz - ez * cy; \
    float dy = ez * cx - ex * cz; \
    float dz = ex * cy - ey * cx; \
    kx = -(cx + alpha * dx) * inv1a2; \
    ky = -(cy + alpha * dy) * inv1a2; \
    kz = -(cz + alpha * dz) * inv1a2; \
} while (0)

#define WRE(DB) do { EB[DB][idx] = (v4f){ex, ey, ez, 0.0f}; } while (0)

#define EASSIGN  ex = mx; ey = my; ez = mz;
#define AINIT    ax = kx; ay = ky; az = kz;
#define AACC2    ax += 2.0f*kx; ay += 2.0f*ky; az += 2.0f*kz;
#define AACC1    ax += kx; ay += ky; az += kz;
#define EHH      ex = mx + hh*kx; ey = my + hh*ky; ez = mz + hh*kz;
#define EHX      ex = mx + h*kx;  ey = my + h*ky;  ez = mz + h*kz;
#define MUPD     mx += h6*ax; my += h6*ay; mz += h6*az;
#define BTSET(S) btx = bxv + (S)*sxv; bty = byv + (S)*syv; btz = bzv + (S)*szv;

// Phase block Q=1..7: wave-cond (uniform), spin, per-lane work, publish.
#define PH(Q, BODY) do { \
    if (dyW <= 8 - (Q)) { \
        SPIN_NBR(g0 + (Q) - 1); \
        if (dOwn <= 8 - (Q)) { BODY } \
        PUB_CTR(g0 + (Q)); \
    } else { PUB_CTR(g0 + (Q)); } \
} while (0)

#define PROBE(I_) do { \
    if (waveP) { \
        float c = pcell ? mx * ms * pm : 0.0f; \
        _Pragma("unroll") \
        for (int off = 32; off > 0; off >>= 1) c += __shfl_down(c, off, 64); \
        if (lane0) atomicAdd(&priv[b * TST + (I_)], c); \
    } \
} while (0)

    for (int i = 0; i < TST; i += 2) {
        const int I = i >> 1;                 // 2-step group index
        const int g0 = I << 3;                // 8 phases per group

        // Halo refresh ONCE per group (cross-block, BEFORE the intra spin so
        // poll latency overlaps other waves' previous-group phases). Skipped
        // at I==0 (m_0 analytic). Miss -> s_sleep(1) backoff.
        if (haloT && I) {
            const v4f* p = pub + (I & 1) * pubStride + slotOff;
            for (;;) {
                v4f hv = ld16_dev(p);
                if (__float_as_int(hv.w) >= I) { mx = hv.x; my = hv.y; mz = hv.z; break; }
                __builtin_amdgcn_s_sleep(1);
            }
        }

        // group-start catch-up: neighbors done reading phase g0-2 data ->
        // safe to overwrite buffer 0 (central waves: exact; far: ample).
        SPIN_NBR(g0 - 1);

        // phase 0: expose m for step A
        if (dOwn <= 8) { BTSET(sigS[i]); EASSIGN; WRE(0); }
        PUB_CTR(g0);

        PH(1, STAGE(0); AINIT; EHH; WRE(1); );            // k1 (A)
        PH(2, STAGE(1); AACC2; EHH; WRE(0); );            // k2 (A)
        PH(3, STAGE(0); AACC2; EHX; WRE(1); );            // k3 (A)

        // phase 4: k4 (A) + m-update + probe + expose m for step B
        if (dyW <= 4) {
            SPIN_NBR(g0 + 3);
            if (dOwn <= 4) { STAGE(1); AACC1; MUPD; }
            PROBE(i);
            if (dOwn <= 4) { BTSET(sigS[i + 1]); EASSIGN; WRE(0); }
            PUB_CTR(g0 + 4);
        } else { PUB_CTR(g0 + 4); }

        PH(5, STAGE(0); AINIT; EHH; WRE(1); );            // k1 (B)
        PH(6, STAGE(1); AACC2; EHH; WRE(0); );            // k2 (B)
        PH(7, STAGE(0); AACC2; EHX; WRE(1); );            // k3 (B)

        // tail: k4 (B) + m-update + probe + stamp publish (central waves only)
        if (dyW <= 0) {
            SPIN_NBR(g0 + 7);
            if (dOwn <= 0) { STAGE(1); AACC1; MUPD; }
            PROBE(i + 1);
            if (own) st16_dev(pub + ((I + 1) & 1) * pubStride + slotOff,
                              (v4f){mx, my, mz, __int_as_float(I + 1)});
        }
    }

    // ---- finalize ----
    __syncthreads();   // TRUE barrier: drains vmcnt -> publishes/atomics done
    if (t == 0) agstorei(&doneA[b], 0x5D0000 | hasPr);

    if (b == 0) {
        if (t < NB) {
            int v;
            for (;;) { v = agloadi(&doneA[t]); if ((v & ~1) == 0x5D0000) break;
                       __builtin_amdgcn_s_sleep(8); }
            pfl[t] = v & 1;
        }
        __syncthreads();
        float ps = 0.0f;
        for (int k = t; k < 65536; k += NT) ps += probe_mask[k];
        #pragma unroll
        for (int off = 32; off > 0; off >>= 1) ps += __shfl_down(ps, off, 64);
        if (lane0) redS[wv] = ps;
        __syncthreads();
        if (t == 0) { float q = 0.0f; for (int w = 0; w < NW; ++w) q += redS[w]; pmsS = q; }
        __syncthreads();
        const float pms = pmsS;
        for (int o = t; o < TST; o += NT) {
            float sm = 0.0f;
            for (int j = 0; j < NB; ++j) if (pfl[j]) sm += agload(&priv[j * TST + o]);
            out[o] = sm / pms;
        }
    }
}

extern "C" void kernel_launch(void* const* d_in, const int* in_sizes, int n_in,
                              void* d_out, int out_size, void* d_ws, size_t ws_size,
                              hipStream_t stream)
{
    const float* signal = (const float*)d_in[0];
    const float* B_ext  = (const float*)d_in[1];
    const float* Msat   = (const float*)d_in[2];
    const float* src    = (const float*)d_in[3];
    const float* probe  = (const float*)d_in[4];
    float* out = (float*)d_out;
    float* ws  = (float*)d_ws;

    void* args[] = { &signal, &B_ext, &Msat, &src, &probe, &out, &ws };
    (void)in_sizes; (void)n_in; (void)out_size; (void)ws_size;

    // 256 blocks (16x16 own tiles, 8-deep halo) x 1024 threads, 1 cell/thread.
    // R13 = R5's proven spin-chain sync + R11's proven cone predication:
    // far-halo waves exhaust their cone budget early, burst-publish their
    // counters and race to the next group's IF$ poll -> poll RTT overlaps
    // central waves' remaining phases (the barrier version stalls the whole
    // block). No in-loop block barriers; cross-block exchange every 2 RK4
    // steps via stamped IF$ slots.
    hipLaunchCooperativeKernel(reinterpret_cast<void*>(mm_solver),
                               dim3(NB), dim3(NT), args, 0, stream);
}